// Round 8
// baseline (490.884 us; speedup 1.0000x reference)
//
#include <hip/hip_runtime.h>
#include <stdint.h>

#define NN 50000
#define NE 600000
#define ND 128
#define NH 512
#define NO 128
#define MPAD 50048  // 391 * 128
#define NB 196      // ceil(NN/256) scan blocks

typedef unsigned short u16;
typedef uint8_t u8;
typedef __attribute__((ext_vector_type(8))) short bf16x8;
typedef __attribute__((ext_vector_type(4))) float f32x4;
typedef __attribute__((ext_vector_type(2))) float f32x2;

__device__ __forceinline__ u16 f2bf(float f) {
  union { float f; uint32_t u; } v; v.f = f;
  uint32_t u = v.u;
  uint32_t r = (u + 0x7fffu + ((u >> 16) & 1u)) >> 16;
  return (u16)r;
}
__device__ __forceinline__ float bf2f(u16 h) {
  union { uint32_t u; float f; } v; v.u = ((uint32_t)h) << 16; return v.f;
}
__device__ __forceinline__ uint64_t f42bfq(float4 v) {
  union { u16 u[4]; uint64_t q; } o;
  o.u[0] = f2bf(v.x); o.u[1] = f2bf(v.y); o.u[2] = f2bf(v.z); o.u[3] = f2bf(v.w);
  return o.q;
}

// ---- fp8 e4m3 (OCP) encode/decode: HW cvt on gfx950, SW fallback ----
#if defined(__has_builtin)
#if __has_builtin(__builtin_amdgcn_cvt_pk_f32_fp8) && __has_builtin(__builtin_amdgcn_cvt_pk_fp8_f32)
#define HW_FP8 1
#endif
#endif
#ifndef HW_FP8
#define HW_FP8 0
#endif

__device__ __forceinline__ u8 f2fp8(float f) {
#if HW_FP8
  return (u8)(__builtin_amdgcn_cvt_pk_fp8_f32(f, f, 0, false) & 0xff);
#else
  union { float f; uint32_t u; } v; v.f = f;
  uint32_t s = v.u >> 31;
  float a = fabsf(f);
  if (a >= 448.f) return (u8)((s << 7) | 0x7e);
  if (a < 0.015625f) {
    uint32_t m = (uint32_t)(a * 512.0f + 0.5f);
    if (m > 7) return (u8)((s << 7) | 8);
    return (u8)((s << 7) | m);
  }
  uint32_t u = v.u & 0x7fffffff;
  uint32_t r = u + 0x7FFFF + ((u >> 20) & 1);
  int e8 = (int)(r >> 23) - 120;
  if (e8 >= 16) return (u8)((s << 7) | 0x7e);
  return (u8)((s << 7) | ((uint32_t)e8 << 3) | ((r >> 20) & 7));
#endif
}

template<bool HI>
__device__ __forceinline__ f32x2 fp8x2_f32(uint32_t w) {
#if HW_FP8
  return __builtin_amdgcn_cvt_pk_f32_fp8((int)w, HI);
#else
  uint32_t h = HI ? (w >> 16) : w;
  f32x2 r;
  for (int i = 0; i < 2; ++i) {
    uint32_t b = (h >> (i * 8)) & 0xff;
    uint32_t s = (b >> 7) & 1, e = (b >> 3) & 15, m = b & 7;
    float t;
    if (e == 0) t = (float)m * 0.001953125f;
    else { union { uint32_t u; float f; } v; v.u = ((e + 120) << 23) | (m << 20); t = v.f; }
    r[i] = s ? -t : t;
  }
  return r;
#endif
}

__device__ __forceinline__ void gld16(const u16* g, u16* l) {
  __builtin_amdgcn_global_load_lds(
      (const __attribute__((address_space(1))) void*)g,
      (__attribute__((address_space(3))) void*)l, 16, 0, 0);
}

// ---------------------------------------------------------------------------
// GEMM: C[M,512] = A[M,K](bf16) @ B^T   B stored transposed [512,K], hi+lo
// A: LDS double-buffered (global_load_lds, XOR-swizzled both-sides),
//    single barrier per K-step (stage k+1 -> compute k -> sync).
// B: weights, L2-resident -> loaded DIRECT global->register per fragment.
// 1-D grid, bijective XCD remap, m=wgid>>2 n=wgid&3 (A-tile L2 reuse).
// EPI 0: relu -> bf16 store ; EPI 1: plain -> fp8 store (H) ;
// EPI 2: relu -> guarded column-sum atomicAdd into sumOut[512]
// ---------------------------------------------------------------------------
template<int K, int EPI>
__global__ __launch_bounds__(256, 3) void gemm_bt(
    const u16* __restrict__ A, const u16* __restrict__ Bhi,
    const u16* __restrict__ Blo, const float* __restrict__ bias,
    u16* __restrict__ outB, u8* __restrict__ outF8,
    float* __restrict__ sumOut)
{
  __shared__ u16 As[2][128 * 64];
  const int nwg  = gridDim.x;
  const int q    = nwg >> 3, r = nwg & 7;
  const int xcd  = blockIdx.x & 7, loc = blockIdx.x >> 3;
  const int wgid = (xcd < r ? xcd * (q + 1) : r * (q + 1) + (xcd - r) * q) + loc;
  const int m0   = (wgid >> 2) * 128;
  const int n0   = (wgid & 3) * 128;

  const int tid  = threadIdx.x;
  const int w    = tid >> 6;
  const int lane = tid & 63;
  const int wm   = (w >> 1) * 64;
  const int wn   = (w & 1) * 64;
  const int l15  = lane & 15;
  const int lh   = lane >> 4;

  // per-wave B row base pointers (rows fixed across K loop)
  const u16* bhp[4];
  const u16* blp[4];
#pragma unroll
  for (int n = 0; n < 4; ++n) {
    const size_t rowoff = (size_t)(n0 + wn + n * 16 + l15) * K;
    bhp[n] = Bhi + rowoff;
    blp[n] = Blo + rowoff;
  }

  const f32x4 z4 = {0.f, 0.f, 0.f, 0.f};
  f32x4 acc[4][4];
#pragma unroll
  for (int m = 0; m < 4; ++m)
#pragma unroll
    for (int n = 0; n < 4; ++n) acc[m][n] = z4;

  const int NK = K / 64;
  // stage A K-step kk into As[kk&1] (pre-swizzled source, linear LDS dest)
  auto stageA = [&](int kk) {
#pragma unroll
    for (int i = 0; i < 4; ++i) {
      const int cc  = i * 256 + w * 64 + lane;     // 16B chunk id
      const int row = cc >> 3;
      const int csw = (cc ^ row) & 7;
      gld16(A + (size_t)(m0 + row) * K + kk * 64 + csw * 8,
            As[kk & 1] + (i * 256 + w * 64) * 8);
    }
  };

  stageA(0);
  __syncthreads();

  for (int kk = 0; kk < NK; ++kk) {
    if (kk + 1 < NK) stageA(kk + 1);
    const u16* as = As[kk & 1];
    const int kb = kk * 64;
#pragma unroll
    for (int ks = 0; ks < 2; ++ks) {
      bf16x8 a[4], bh[4], bl[4];
#pragma unroll
      for (int n = 0; n < 4; ++n) {
        bh[n] = *(const bf16x8*)(bhp[n] + kb + ks * 32 + lh * 8);
        bl[n] = *(const bf16x8*)(blp[n] + kb + ks * 32 + lh * 8);
      }
#pragma unroll
      for (int m = 0; m < 4; ++m) {
        const int row = wm + m * 16 + l15;
        const int ch  = (ks * 4 + lh) ^ (row & 7);
        a[m] = *(const bf16x8*)&as[row * 64 + ch * 8];
      }
#pragma unroll
      for (int m = 0; m < 4; ++m)
#pragma unroll
        for (int n = 0; n < 4; ++n) {
          acc[m][n] = __builtin_amdgcn_mfma_f32_16x16x32_bf16(a[m], bh[n], acc[m][n], 0, 0, 0);
          acc[m][n] = __builtin_amdgcn_mfma_f32_16x16x32_bf16(a[m], bl[n], acc[m][n], 0, 0, 0);
        }
    }
    __syncthreads();
  }

  if (EPI == 2) {
#pragma unroll
    for (int n = 0; n < 4; ++n) {
      const int gc = n0 + wn + n * 16 + l15;
      const float bv = bias[gc];
      float p = 0.f;
#pragma unroll
      for (int m = 0; m < 4; ++m) {
        const int rbase = m0 + wm + m * 16 + lh * 4;
#pragma unroll
        for (int j = 0; j < 4; ++j) {
          if (rbase + j < NN) p += fmaxf(acc[m][n][j] + bv, 0.f);
        }
      }
      p += __shfl_xor(p, 16);
      p += __shfl_xor(p, 32);
      if (lane < 16) atomicAdd(&sumOut[gc], p);
    }
  } else {
#pragma unroll
    for (int m = 0; m < 4; ++m) {
#pragma unroll
      for (int j = 0; j < 4; ++j) {
        const int gr = m0 + wm + m * 16 + lh * 4 + j;
#pragma unroll
        for (int n = 0; n < 4; ++n) {
          const int gc = n0 + wn + n * 16 + l15;
          const float v = acc[m][n][j] + bias[gc];
          if (EPI == 0) outB[(size_t)gr * NH + gc] = f2bf(fmaxf(v, 0.f));
          else          outF8[(size_t)gr * NH + gc] = f2fp8(v);
        }
      }
    }
  }
}

// f32 weight [Kd,Nd] -> transposed bf16 hi/lo [Nd,Kd]
__global__ void cvtWT(const float* __restrict__ W, u16* __restrict__ Thi,
                      u16* __restrict__ Tlo, int Kd, int Nd) {
  int t = blockIdx.x * 256 + threadIdx.x;
  if (t >= Kd * Nd) return;
  int k = t / Nd, n = t - k * Nd;
  float wv = W[t];
  u16 hi = f2bf(wv);
  float lo = wv - bf2f(hi);
  Thi[n * Kd + k] = hi;
  Tlo[n * Kd + k] = f2bf(lo);
}

// x f32 [NN][128] -> bf16 [MPAD][128] (pad rows zero); 4 cols/thread
__global__ void cvt_x(const float4* __restrict__ x4, uint64_t* __restrict__ xb) {
  int t = blockIdx.x * 256 + threadIdx.x;
  if (t >= MPAD * 32) return;
  int row = t >> 5;
  uint64_t qv = 0;
  if (row < NN) qv = f42bfq(x4[t]);
  xb[t] = qv;
}

// ---------------- CSR construction ----------------
__global__ void hist_dst(const int* __restrict__ ei, int* __restrict__ deg) {
  int e = blockIdx.x * 256 + threadIdx.x;
  if (e < NE) atomicAdd(&deg[ei[NE + e]], 1);
}

__global__ void deg_partial(const int* __restrict__ deg, int* __restrict__ bsum) {
  const int i = blockIdx.x * 256 + threadIdx.x;
  int v = (i < NN) ? deg[i] : 0;
#pragma unroll
  for (int o = 1; o < 64; o <<= 1) v += __shfl_xor(v, o);
  __shared__ int ws[4];
  if ((threadIdx.x & 63) == 0) ws[threadIdx.x >> 6] = v;
  __syncthreads();
  if (threadIdx.x == 0) bsum[blockIdx.x] = ws[0] + ws[1] + ws[2] + ws[3];
}

__global__ void scan_bsum(const int* __restrict__ bsum, int* __restrict__ boff,
                          int* __restrict__ rowptr) {
  __shared__ int s[256];
  const int t = threadIdx.x;
  int v = (t < NB) ? bsum[t] : 0;
  s[t] = v;
  __syncthreads();
  for (int o = 1; o < 256; o <<= 1) {
    int u = (t >= o) ? s[t - o] : 0;
    __syncthreads();
    s[t] += u;
    __syncthreads();
  }
  if (t < NB) boff[t] = s[t] - v;
  if (t == 0) rowptr[NN] = NE;
}

__global__ void scan_apply(const int* __restrict__ deg, const int* __restrict__ boff,
                           int* __restrict__ rowptr, int* __restrict__ cursor) {
  __shared__ int s[256];
  const int t = threadIdx.x;
  const int i = blockIdx.x * 256 + t;
  int v = (i < NN) ? deg[i] : 0;
  s[t] = v;
  __syncthreads();
  for (int o = 1; o < 256; o <<= 1) {
    int u = (t >= o) ? s[t - o] : 0;
    __syncthreads();
    s[t] += u;
    __syncthreads();
  }
  if (i < NN) {
    int ex = boff[blockIdx.x] + s[t] - v;
    rowptr[i] = ex;
    cursor[i] = ex;
  }
}

__global__ void fill_csr(const int* __restrict__ ei, int* __restrict__ cursor,
                         int* __restrict__ csr) {
  int e = blockIdx.x * 256 + threadIdx.x;
  if (e >= NE) return;
  int d = ei[NE + e];
  int p = atomicAdd(&cursor[d], 1);
  csr[p] = ei[e];
}

// ---------------- gather-reduce aggregations ----------------
// conv1: hb1[i][:] = bf16( xb[i][:] + sum_{e} xb[csr[e]][:] )  (xb bf16, dim 128)
__global__ __launch_bounds__(256) void gather_x(
    const u16* __restrict__ xb, const int* __restrict__ rowptr,
    const int* __restrict__ csr, u16* __restrict__ hb1) {
  const int wid  = blockIdx.x * 4 + (threadIdx.x >> 6);
  const int lane = threadIdx.x & 63;
  if (wid >= MPAD) return;
  float a0 = 0.f, a1 = 0.f;
  if (wid < NN) {
    uint32_t v = *(const uint32_t*)(xb + (size_t)wid * ND + lane * 2);
    a0 = bf2f((u16)v); a1 = bf2f((u16)(v >> 16));
    const int beg = rowptr[wid], end = rowptr[wid + 1];
    int e = beg;
    for (; e + 1 < end; e += 2) {
      int s0 = csr[e], s1 = csr[e + 1];
      uint32_t v0 = *(const uint32_t*)(xb + (size_t)s0 * ND + lane * 2);
      uint32_t v1 = *(const uint32_t*)(xb + (size_t)s1 * ND + lane * 2);
      a0 += bf2f((u16)v0) + bf2f((u16)v1);
      a1 += bf2f((u16)(v0 >> 16)) + bf2f((u16)(v1 >> 16));
    }
    if (e < end) {
      int s0 = csr[e];
      uint32_t v0 = *(const uint32_t*)(xb + (size_t)s0 * ND + lane * 2);
      a0 += bf2f((u16)v0);
      a1 += bf2f((u16)(v0 >> 16));
    }
  }
  uint32_t o = (uint32_t)f2bf(a0) | ((uint32_t)f2bf(a1) << 16);
  *(uint32_t*)(hb1 + (size_t)wid * ND + lane * 2) = o;
}

__device__ __forceinline__ void acc_fp8x8(float* acc, uint2 v) {
  f32x2 p;
  p = fp8x2_f32<false>(v.x); acc[0] += p.x; acc[1] += p.y;
  p = fp8x2_f32<true >(v.x); acc[2] += p.x; acc[3] += p.y;
  p = fp8x2_f32<false>(v.y); acc[4] += p.x; acc[5] += p.y;
  p = fp8x2_f32<true >(v.y); acc[6] += p.x; acc[7] += p.y;
}

// conv2: r2[i][:] = bf16( H8[i][:] + sum_{e} H8[csr[e]][:] )  (H8 fp8, dim 512)
__global__ __launch_bounds__(256) void gather_h(
    const u8* __restrict__ H8, const int* __restrict__ rowptr,
    const int* __restrict__ csr, u16* __restrict__ r2) {
  const int wid  = blockIdx.x * 4 + (threadIdx.x >> 6);
  const int lane = threadIdx.x & 63;
  if (wid >= MPAD) return;
  float acc[8];
#pragma unroll
  for (int j = 0; j < 8; ++j) acc[j] = 0.f;
  if (wid < NN) {
    acc_fp8x8(acc, *(const uint2*)(H8 + (size_t)wid * NH + lane * 8));
    const int beg = rowptr[wid], end = rowptr[wid + 1];
    int e = beg;
    for (; e + 1 < end; e += 2) {
      int s0 = csr[e], s1 = csr[e + 1];
      uint2 v0 = *(const uint2*)(H8 + (size_t)s0 * NH + lane * 8);
      uint2 v1 = *(const uint2*)(H8 + (size_t)s1 * NH + lane * 8);
      acc_fp8x8(acc, v0);
      acc_fp8x8(acc, v1);
    }
    if (e < end) {
      int s0 = csr[e];
      acc_fp8x8(acc, *(const uint2*)(H8 + (size_t)s0 * NH + lane * 8));
    }
  }
  union { u16 u[8]; uint4 q; } o;
#pragma unroll
  for (int j = 0; j < 8; ++j) o.u[j] = f2bf(acc[j]);
  *(uint4*)(r2 + (size_t)wid * NH + lane * 8) = o.q;
}

// out[128] = ((s/NN) @ W2b + b2b) @ Wf + bf   (all f32)
__global__ void final_fuse(const float* __restrict__ s, const float* __restrict__ W2b,
                           const float* __restrict__ b2b, const float* __restrict__ Wf,
                           const float* __restrict__ bfv, float* __restrict__ out) {
  __shared__ float pooled[NH];
  const int j = threadIdx.x;
  const float invN = 1.0f / (float)NN;
  float acc = b2b[j];
  for (int k = 0; k < NH; ++k) acc += s[k] * invN * W2b[k * NH + j];
  pooled[j] = acc;
  __syncthreads();
  if (j < NO) {
    float o = bfv[j];
    for (int k = 0; k < NH; ++k) o += pooled[k] * Wf[k * NO + j];
    out[j] = o;
  }
}

__global__ void ws_sentinel(float* out) {
  if (threadIdx.x < NO) out[threadIdx.x] = -12345.0f;
}

extern "C" void kernel_launch(void* const* d_in, const int* in_sizes, int n_in,
                              void* d_out, int out_size, void* d_ws, size_t ws_size,
                              hipStream_t stream) {
  const float* x   = (const float*)d_in[0];
  const int*   ei  = (const int*)d_in[1];
  const float* W1a = (const float*)d_in[2];
  const float* b1a = (const float*)d_in[3];
  const float* W1b = (const float*)d_in[4];
  const float* b1b = (const float*)d_in[5];
  const float* W2a = (const float*)d_in[6];
  const float* b2a = (const float*)d_in[7];
  const float* W2b = (const float*)d_in[8];
  const float* b2b = (const float*)d_in[9];
  const float* Wf  = (const float*)d_in[10];
  const float* bfv = (const float*)d_in[11];
  float* out = (float*)d_out;

  const size_t XB  = (size_t)MPAD * ND * 2;  // 12.8 MB bf16 x
  const size_t HB1 = (size_t)MPAD * ND * 2;  // 12.8 MB bf16 agg1
  const size_t RB  = (size_t)MPAD * NH * 2;  // 51.25 MB bf16 (r1, then r2)
  const size_t H8B = (size_t)MPAD * NH;      // 25.6 MB fp8 (h1)
  const size_t WB  = 2 * (size_t)NH * ND * 2 + 4 * (size_t)NH * NH * 2;
  const size_t CSRB = (size_t)(NN + 1) * 4 + 2 * (size_t)NN * 4 + (size_t)NE * 4
                      + 2 * (size_t)NB * 4;
  const size_t NEED = XB + HB1 + RB + H8B + WB + CSRB + NH * 4 + 32 * 256;
  if (ws_size < NEED) {
    ws_sentinel<<<1, 128, 0, stream>>>(out);
    return;
  }

  char* ws = (char*)d_ws;
  size_t off = 0;
  auto take = [&](size_t bytes) {
    char* p = ws + off;
    off = (off + bytes + 255) & ~(size_t)255;
    return p;
  };
  u16* xb  = (u16*)take(XB);
  u16* hb1 = (u16*)take(HB1);
  u16* R   = (u16*)take(RB);
  u8*  H8  = (u8*)take(H8B);
  u16* W1aT_hi = (u16*)take((size_t)NH * ND * 2);
  u16* W1aT_lo = (u16*)take((size_t)NH * ND * 2);
  u16* W1bT_hi = (u16*)take((size_t)NH * NH * 2);
  u16* W1bT_lo = (u16*)take((size_t)NH * NH * 2);
  u16* W2aT_hi = (u16*)take((size_t)NH * NH * 2);
  u16* W2aT_lo = (u16*)take((size_t)NH * NH * 2);
  int* deg    = (int*)take((size_t)NN * 4);
  int* cursor = (int*)take((size_t)NN * 4);
  int* rowptr = (int*)take((size_t)(NN + 1) * 4);
  int* csr    = (int*)take((size_t)NE * 4);
  int* bsum   = (int*)take((size_t)NB * 4);
  int* boff   = (int*)take((size_t)NB * 4);
  float* svec = (float*)take((size_t)NH * 4);

  (void)hipMemsetAsync(svec, 0, NH * 4, stream);
  (void)hipMemsetAsync(deg, 0, (size_t)NN * 4, stream);

  // weights -> transposed bf16 hi/lo; x -> bf16 padded
  cvtWT<<<(ND * NH + 255) / 256, 256, 0, stream>>>(W1a, W1aT_hi, W1aT_lo, ND, NH);
  cvtWT<<<(NH * NH + 255) / 256, 256, 0, stream>>>(W1b, W1bT_hi, W1bT_lo, NH, NH);
  cvtWT<<<(NH * NH + 255) / 256, 256, 0, stream>>>(W2a, W2aT_hi, W2aT_lo, NH, NH);
  cvt_x<<<(MPAD * 32 + 255) / 256, 256, 0, stream>>>((const float4*)x, (uint64_t*)xb);

  // CSR: deg -> parallel exclusive scan -> rowptr/cursor -> csr
  hist_dst<<<(NE + 255) / 256, 256, 0, stream>>>(ei, deg);
  deg_partial<<<NB, 256, 0, stream>>>(deg, bsum);
  scan_bsum<<<1, 256, 0, stream>>>(bsum, boff, rowptr);
  scan_apply<<<NB, 256, 0, stream>>>(deg, boff, rowptr, cursor);
  fill_csr<<<(NE + 255) / 256, 256, 0, stream>>>(ei, cursor, csr);

  // conv1: gather (bf16) + MLP; h1 stored fp8
  gather_x<<<(MPAD + 3) / 4, 256, 0, stream>>>(xb, rowptr, csr, hb1);
  gemm_bt<ND, 0><<<(MPAD / 128) * 4, 256, 0, stream>>>(hb1, W1aT_hi, W1aT_lo, b1a, R, nullptr, nullptr);
  gemm_bt<NH, 1><<<(MPAD / 128) * 4, 256, 0, stream>>>(R, W1bT_hi, W1bT_lo, b1b, nullptr, H8, nullptr);

  // conv2: gather fp8 (r2 overwrites R) + first layer fused with relu+mean-pool
  gather_h<<<(MPAD + 3) / 4, 256, 0, stream>>>(H8, rowptr, csr, R);
  gemm_bt<NH, 2><<<(MPAD / 128) * 4, 256, 0, stream>>>(R, W2aT_hi, W2aT_lo, b2a, nullptr, nullptr, svec);

  // pooled @ W2b + b2b then @ Wf + bf
  final_fuse<<<1, NH, 0, stream>>>(svec, W2b, b2b, Wf, bfv, out);
}

// Round 9
// 355.933 us; speedup vs baseline: 1.3791x; 1.3791x over previous
//
#include <hip/hip_runtime.h>
#include <stdint.h>

#define NN 50000
#define NE 600000
#define ND 128
#define NH 512
#define NO 128
#define MPAD 50048  // 391 * 128
#define NB 196      // ceil(NN/256) scan blocks

typedef unsigned short u16;
typedef uint8_t u8;
typedef __attribute__((ext_vector_type(8))) short bf16x8;
typedef __attribute__((ext_vector_type(4))) float f32x4;
typedef __attribute__((ext_vector_type(2))) float f32x2;

__device__ __forceinline__ u16 f2bf(float f) {
  union { float f; uint32_t u; } v; v.f = f;
  uint32_t u = v.u;
  uint32_t r = (u + 0x7fffu + ((u >> 16) & 1u)) >> 16;
  return (u16)r;
}
__device__ __forceinline__ float bf2f(u16 h) {
  union { uint32_t u; float f; } v; v.u = ((uint32_t)h) << 16; return v.f;
}
__device__ __forceinline__ uint64_t f42bfq(float4 v) {
  union { u16 u[4]; uint64_t q; } o;
  o.u[0] = f2bf(v.x); o.u[1] = f2bf(v.y); o.u[2] = f2bf(v.z); o.u[3] = f2bf(v.w);
  return o.q;
}

// ---- fp8 e4m3 (OCP) encode/decode: HW cvt on gfx950, SW fallback ----
#if defined(__has_builtin)
#if __has_builtin(__builtin_amdgcn_cvt_pk_f32_fp8) && __has_builtin(__builtin_amdgcn_cvt_pk_fp8_f32)
#define HW_FP8 1
#endif
#endif
#ifndef HW_FP8
#define HW_FP8 0
#endif

__device__ __forceinline__ u8 f2fp8(float f) {
#if HW_FP8
  return (u8)(__builtin_amdgcn_cvt_pk_fp8_f32(f, f, 0, false) & 0xff);
#else
  union { float f; uint32_t u; } v; v.f = f;
  uint32_t s = v.u >> 31;
  float a = fabsf(f);
  if (a >= 448.f) return (u8)((s << 7) | 0x7e);
  if (a < 0.015625f) {
    uint32_t m = (uint32_t)(a * 512.0f + 0.5f);
    if (m > 7) return (u8)((s << 7) | 8);
    return (u8)((s << 7) | m);
  }
  uint32_t u = v.u & 0x7fffffff;
  uint32_t r = u + 0x7FFFF + ((u >> 20) & 1);
  int e8 = (int)(r >> 23) - 120;
  if (e8 >= 16) return (u8)((s << 7) | 0x7e);
  return (u8)((s << 7) | ((uint32_t)e8 << 3) | ((r >> 20) & 7));
#endif
}

template<bool HI>
__device__ __forceinline__ f32x2 fp8x2_f32(uint32_t w) {
#if HW_FP8
  return __builtin_amdgcn_cvt_pk_f32_fp8((int)w, HI);
#else
  uint32_t h = HI ? (w >> 16) : w;
  f32x2 r;
  for (int i = 0; i < 2; ++i) {
    uint32_t b = (h >> (i * 8)) & 0xff;
    uint32_t s = (b >> 7) & 1, e = (b >> 3) & 15, m = b & 7;
    float t;
    if (e == 0) t = (float)m * 0.001953125f;
    else { union { uint32_t u; float f; } v; v.u = ((e + 120) << 23) | (m << 20); t = v.f; }
    r[i] = s ? -t : t;
  }
  return r;
#endif
}

__device__ __forceinline__ void gld16(const u16* g, u16* l) {
  __builtin_amdgcn_global_load_lds(
      (const __attribute__((address_space(1))) void*)g,
      (__attribute__((address_space(3))) void*)l, 16, 0, 0);
}

// ---------------------------------------------------------------------------
// GEMM: C[M,512] = A[M,K](bf16) @ B^T   B stored transposed [512,K], hi+lo
// (round-7 proven structure: A,Bhi,Blo staged via global_load_lds,
//  XOR-swizzled both-sides, 2 barriers/K-step; 1-D grid + bijective XCD
//  remap, m=wgid>>2 n=wgid&3 for A-tile L2 reuse.)
// EPI 0: relu -> bf16 store ; EPI 1: plain -> fp8 store (H) ;
// EPI 2: relu -> guarded column-sum atomicAdd into sumOut[512]
// ---------------------------------------------------------------------------
template<int K, int EPI>
__global__ __launch_bounds__(256) void gemm_bt(
    const u16* __restrict__ A, const u16* __restrict__ Bhi,
    const u16* __restrict__ Blo, const float* __restrict__ bias,
    u16* __restrict__ outB, u8* __restrict__ outF8,
    float* __restrict__ sumOut)
{
  __shared__ u16 As[128 * 64];
  __shared__ u16 BsH[128 * 64];
  __shared__ u16 BsL[128 * 64];
  const int nwg  = gridDim.x;
  const int q    = nwg >> 3, r = nwg & 7;
  const int xcd  = blockIdx.x & 7, loc = blockIdx.x >> 3;
  const int wgid = (xcd < r ? xcd * (q + 1) : r * (q + 1) + (xcd - r) * q) + loc;
  const int m0   = (wgid >> 2) * 128;
  const int n0   = (wgid & 3) * 128;

  const int tid  = threadIdx.x;
  const int w    = tid >> 6;
  const int lane = tid & 63;
  const int wm   = (w >> 1) * 64;
  const int wn   = (w & 1) * 64;
  const int l15  = lane & 15;
  const int lh   = lane >> 4;

  const f32x4 z4 = {0.f, 0.f, 0.f, 0.f};
  f32x4 acc[4][4];
#pragma unroll
  for (int m = 0; m < 4; ++m)
#pragma unroll
    for (int n = 0; n < 4; ++n) acc[m][n] = z4;

  for (int k0 = 0; k0 < K; k0 += 64) {
#pragma unroll
    for (int i = 0; i < 4; ++i) {
      const int cc  = i * 256 + w * 64 + lane;     // 16B chunk id, lane-contig
      const int row = cc >> 3;
      const int csw = (cc ^ row) & 7;              // swizzled source chunk
      const int ldsbase = (i * 256 + w * 64) * 8;  // u16 units, wave-uniform (linear)
      gld16(A   + (size_t)(m0 + row) * K + k0 + csw * 8, As  + ldsbase);
      gld16(Bhi + (size_t)(n0 + row) * K + k0 + csw * 8, BsH + ldsbase);
      gld16(Blo + (size_t)(n0 + row) * K + k0 + csw * 8, BsL + ldsbase);
    }
    __syncthreads();
#pragma unroll
    for (int ks = 0; ks < 2; ++ks) {
      bf16x8 a[4], bh[4], bl[4];
#pragma unroll
      for (int m = 0; m < 4; ++m) {
        const int row = wm + m * 16 + l15;
        const int ch  = (ks * 4 + lh) ^ (row & 7);
        a[m] = *(const bf16x8*)&As[row * 64 + ch * 8];
      }
#pragma unroll
      for (int n = 0; n < 4; ++n) {
        const int row = wn + n * 16 + l15;
        const int ch  = (ks * 4 + lh) ^ (row & 7);
        bh[n] = *(const bf16x8*)&BsH[row * 64 + ch * 8];
        bl[n] = *(const bf16x8*)&BsL[row * 64 + ch * 8];
      }
#pragma unroll
      for (int m = 0; m < 4; ++m)
#pragma unroll
        for (int n = 0; n < 4; ++n) {
          acc[m][n] = __builtin_amdgcn_mfma_f32_16x16x32_bf16(a[m], bh[n], acc[m][n], 0, 0, 0);
          acc[m][n] = __builtin_amdgcn_mfma_f32_16x16x32_bf16(a[m], bl[n], acc[m][n], 0, 0, 0);
        }
    }
    __syncthreads();
  }

  if (EPI == 2) {
#pragma unroll
    for (int n = 0; n < 4; ++n) {
      const int gc = n0 + wn + n * 16 + l15;
      const float bv = bias[gc];
      float p = 0.f;
#pragma unroll
      for (int m = 0; m < 4; ++m) {
        const int rbase = m0 + wm + m * 16 + lh * 4;
#pragma unroll
        for (int j = 0; j < 4; ++j) {
          if (rbase + j < NN) p += fmaxf(acc[m][n][j] + bv, 0.f);
        }
      }
      p += __shfl_xor(p, 16);
      p += __shfl_xor(p, 32);
      if (lane < 16) atomicAdd(&sumOut[gc], p);
    }
  } else {
#pragma unroll
    for (int m = 0; m < 4; ++m) {
#pragma unroll
      for (int j = 0; j < 4; ++j) {
        const int gr = m0 + wm + m * 16 + lh * 4 + j;
#pragma unroll
        for (int n = 0; n < 4; ++n) {
          const int gc = n0 + wn + n * 16 + l15;
          const float v = acc[m][n][j] + bias[gc];
          if (EPI == 0) outB[(size_t)gr * NH + gc] = f2bf(fmaxf(v, 0.f));
          else          outF8[(size_t)gr * NH + gc] = f2fp8(v);
        }
      }
    }
  }
}

// ---------------------------------------------------------------------------
// Fused prologue prep: one launch does
//  region 0: W1a [128x512]  -> W1aT hi/lo   (256 blocks)
//  region 1: W1b [512x512]  -> W1bT hi/lo   (1024 blocks)
//  region 2: W2a [512x512]  -> W2aT hi/lo   (1024 blocks)
//  region 3: x f32 -> bf16 padded           (6256 blocks, 4 cols/thread)
// ---------------------------------------------------------------------------
struct PrepArgs {
  const float* W1a; u16* W1aT_hi; u16* W1aT_lo;
  const float* W1b; u16* W1bT_hi; u16* W1bT_lo;
  const float* W2a; u16* W2aT_hi; u16* W2aT_lo;
  const float4* x4; uint64_t* xb;
};

__device__ __forceinline__ void cvtWT_one(const float* W, u16* Thi, u16* Tlo,
                                          int Kd, int Nd, int t) {
  if (t >= Kd * Nd) return;
  int k = t / Nd, n = t - k * Nd;
  float wv = W[t];
  u16 hi = f2bf(wv);
  float lo = wv - bf2f(hi);
  Thi[n * Kd + k] = hi;
  Tlo[n * Kd + k] = f2bf(lo);
}

__global__ __launch_bounds__(256) void prep_all(PrepArgs p) {
  const int bid = blockIdx.x;
  if (bid < 256) {
    cvtWT_one(p.W1a, p.W1aT_hi, p.W1aT_lo, ND, NH, bid * 256 + threadIdx.x);
  } else if (bid < 1280) {
    cvtWT_one(p.W1b, p.W1bT_hi, p.W1bT_lo, NH, NH, (bid - 256) * 256 + threadIdx.x);
  } else if (bid < 2304) {
    cvtWT_one(p.W2a, p.W2aT_hi, p.W2aT_lo, NH, NH, (bid - 1280) * 256 + threadIdx.x);
  } else {
    int t = (bid - 2304) * 256 + threadIdx.x;
    if (t >= MPAD * 32) return;
    int row = t >> 5;
    uint64_t qv = 0;
    if (row < NN) qv = f42bfq(p.x4[t]);
    p.xb[t] = qv;
  }
}

// ---------------- CSR construction ----------------
__global__ void hist_dst(const int* __restrict__ ei, int* __restrict__ deg) {
  int e = blockIdx.x * 256 + threadIdx.x;
  if (e < NE) atomicAdd(&deg[ei[NE + e]], 1);
}

__global__ void deg_partial(const int* __restrict__ deg, int* __restrict__ bsum) {
  const int i = blockIdx.x * 256 + threadIdx.x;
  int v = (i < NN) ? deg[i] : 0;
#pragma unroll
  for (int o = 1; o < 64; o <<= 1) v += __shfl_xor(v, o);
  __shared__ int ws[4];
  if ((threadIdx.x & 63) == 0) ws[threadIdx.x >> 6] = v;
  __syncthreads();
  if (threadIdx.x == 0) bsum[blockIdx.x] = ws[0] + ws[1] + ws[2] + ws[3];
}

__global__ void scan_bsum(const int* __restrict__ bsum, int* __restrict__ boff,
                          int* __restrict__ rowptr) {
  __shared__ int s[256];
  const int t = threadIdx.x;
  int v = (t < NB) ? bsum[t] : 0;
  s[t] = v;
  __syncthreads();
  for (int o = 1; o < 256; o <<= 1) {
    int u = (t >= o) ? s[t - o] : 0;
    __syncthreads();
    s[t] += u;
    __syncthreads();
  }
  if (t < NB) boff[t] = s[t] - v;
  if (t == 0) rowptr[NN] = NE;
}

__global__ void scan_apply(const int* __restrict__ deg, const int* __restrict__ boff,
                           int* __restrict__ rowptr, int* __restrict__ cursor) {
  __shared__ int s[256];
  const int t = threadIdx.x;
  const int i = blockIdx.x * 256 + t;
  int v = (i < NN) ? deg[i] : 0;
  s[t] = v;
  __syncthreads();
  for (int o = 1; o < 256; o <<= 1) {
    int u = (t >= o) ? s[t - o] : 0;
    __syncthreads();
    s[t] += u;
    __syncthreads();
  }
  if (i < NN) {
    int ex = boff[blockIdx.x] + s[t] - v;
    rowptr[i] = ex;
    cursor[i] = ex;
  }
}

__global__ void fill_csr(const int* __restrict__ ei, int* __restrict__ cursor,
                         int* __restrict__ csr) {
  int e = blockIdx.x * 256 + threadIdx.x;
  if (e >= NE) return;
  int d = ei[NE + e];
  int p = atomicAdd(&cursor[d], 1);
  csr[p] = ei[e];
}

// ---------------- gather-reduce aggregations ----------------
// conv1: hb1[i][:] = bf16( xb[i][:] + sum_{e} xb[csr[e]][:] )  (xb bf16, dim 128)
__global__ __launch_bounds__(256) void gather_x(
    const u16* __restrict__ xb, const int* __restrict__ rowptr,
    const int* __restrict__ csr, u16* __restrict__ hb1) {
  const int wid  = blockIdx.x * 4 + (threadIdx.x >> 6);
  const int lane = threadIdx.x & 63;
  if (wid >= MPAD) return;
  float a0 = 0.f, a1 = 0.f;
  if (wid < NN) {
    uint32_t v = *(const uint32_t*)(xb + (size_t)wid * ND + lane * 2);
    a0 = bf2f((u16)v); a1 = bf2f((u16)(v >> 16));
    const int beg = rowptr[wid], end = rowptr[wid + 1];
    int e = beg;
    for (; e + 1 < end; e += 2) {
      int s0 = csr[e], s1 = csr[e + 1];
      uint32_t v0 = *(const uint32_t*)(xb + (size_t)s0 * ND + lane * 2);
      uint32_t v1 = *(const uint32_t*)(xb + (size_t)s1 * ND + lane * 2);
      a0 += bf2f((u16)v0) + bf2f((u16)v1);
      a1 += bf2f((u16)(v0 >> 16)) + bf2f((u16)(v1 >> 16));
    }
    if (e < end) {
      int s0 = csr[e];
      uint32_t v0 = *(const uint32_t*)(xb + (size_t)s0 * ND + lane * 2);
      a0 += bf2f((u16)v0);
      a1 += bf2f((u16)(v0 >> 16));
    }
  }
  uint32_t o = (uint32_t)f2bf(a0) | ((uint32_t)f2bf(a1) << 16);
  *(uint32_t*)(hb1 + (size_t)wid * ND + lane * 2) = o;
}

// fp8 x8 decode -> packed f32x2 accumulate (v_pk_add_f32)
__device__ __forceinline__ void acc_fp8x8(f32x2* acc, uint2 v) {
  acc[0] += fp8x2_f32<false>(v.x);
  acc[1] += fp8x2_f32<true >(v.x);
  acc[2] += fp8x2_f32<false>(v.y);
  acc[3] += fp8x2_f32<true >(v.y);
}

// conv2: r2[i][:] = bf16( H8[i][:] + sum_{e} H8[csr[e]][:] )  (H8 fp8, dim 512)
__global__ __launch_bounds__(256) void gather_h(
    const u8* __restrict__ H8, const int* __restrict__ rowptr,
    const int* __restrict__ csr, u16* __restrict__ r2) {
  const int wid  = blockIdx.x * 4 + (threadIdx.x >> 6);
  const int lane = threadIdx.x & 63;
  if (wid >= MPAD) return;
  f32x2 acc[4];
#pragma unroll
  for (int j = 0; j < 4; ++j) acc[j] = (f32x2){0.f, 0.f};
  if (wid < NN) {
    acc_fp8x8(acc, *(const uint2*)(H8 + (size_t)wid * NH + lane * 8));
    const int beg = rowptr[wid], end = rowptr[wid + 1];
    int e = beg;
    for (; e + 1 < end; e += 2) {
      int s0 = csr[e], s1 = csr[e + 1];
      uint2 v0 = *(const uint2*)(H8 + (size_t)s0 * NH + lane * 8);
      uint2 v1 = *(const uint2*)(H8 + (size_t)s1 * NH + lane * 8);
      acc_fp8x8(acc, v0);
      acc_fp8x8(acc, v1);
    }
    if (e < end) {
      int s0 = csr[e];
      acc_fp8x8(acc, *(const uint2*)(H8 + (size_t)s0 * NH + lane * 8));
    }
  }
  union { u16 u[8]; uint4 q; } o;
#pragma unroll
  for (int j = 0; j < 4; ++j) {
    o.u[j * 2]     = f2bf(acc[j].x);
    o.u[j * 2 + 1] = f2bf(acc[j].y);
  }
  *(uint4*)(r2 + (size_t)wid * NH + lane * 8) = o.q;
}

// out[128] = ((s/NN) @ W2b + b2b) @ Wf + bf   (all f32)
__global__ void final_fuse(const float* __restrict__ s, const float* __restrict__ W2b,
                           const float* __restrict__ b2b, const float* __restrict__ Wf,
                           const float* __restrict__ bfv, float* __restrict__ out) {
  __shared__ float pooled[NH];
  const int j = threadIdx.x;
  const float invN = 1.0f / (float)NN;
  float acc = b2b[j];
  for (int k = 0; k < NH; ++k) acc += s[k] * invN * W2b[k * NH + j];
  pooled[j] = acc;
  __syncthreads();
  if (j < NO) {
    float o = bfv[j];
    for (int k = 0; k < NH; ++k) o += pooled[k] * Wf[k * NO + j];
    out[j] = o;
  }
}

__global__ void ws_sentinel(float* out) {
  if (threadIdx.x < NO) out[threadIdx.x] = -12345.0f;
}

extern "C" void kernel_launch(void* const* d_in, const int* in_sizes, int n_in,
                              void* d_out, int out_size, void* d_ws, size_t ws_size,
                              hipStream_t stream) {
  const float* x   = (const float*)d_in[0];
  const int*   ei  = (const int*)d_in[1];
  const float* W1a = (const float*)d_in[2];
  const float* b1a = (const float*)d_in[3];
  const float* W1b = (const float*)d_in[4];
  const float* b1b = (const float*)d_in[5];
  const float* W2a = (const float*)d_in[6];
  const float* b2a = (const float*)d_in[7];
  const float* W2b = (const float*)d_in[8];
  const float* b2b = (const float*)d_in[9];
  const float* Wf  = (const float*)d_in[10];
  const float* bfv = (const float*)d_in[11];
  float* out = (float*)d_out;

  const size_t XB  = (size_t)MPAD * ND * 2;  // 12.8 MB bf16 x
  const size_t HB1 = (size_t)MPAD * ND * 2;  // 12.8 MB bf16 agg1
  const size_t RB  = (size_t)MPAD * NH * 2;  // 51.25 MB bf16 (r1, then r2)
  const size_t H8B = (size_t)MPAD * NH;      // 25.6 MB fp8 (h1)
  const size_t WB  = 2 * (size_t)NH * ND * 2 + 4 * (size_t)NH * NH * 2;
  const size_t CSRB = (size_t)(NN + 1) * 4 + 2 * (size_t)NN * 4 + (size_t)NE * 4
                      + 2 * (size_t)NB * 4;
  const size_t NEED = XB + HB1 + RB + H8B + WB + CSRB + NH * 4 + 32 * 256;
  if (ws_size < NEED) {
    ws_sentinel<<<1, 128, 0, stream>>>(out);
    return;
  }

  char* ws = (char*)d_ws;
  size_t off = 0;
  auto take = [&](size_t bytes) {
    char* p = ws + off;
    off = (off + bytes + 255) & ~(size_t)255;
    return p;
  };
  u16* xb  = (u16*)take(XB);
  u16* hb1 = (u16*)take(HB1);
  u16* R   = (u16*)take(RB);
  u8*  H8  = (u8*)take(H8B);
  u16* W1aT_hi = (u16*)take((size_t)NH * ND * 2);
  u16* W1aT_lo = (u16*)take((size_t)NH * ND * 2);
  u16* W1bT_hi = (u16*)take((size_t)NH * NH * 2);
  u16* W1bT_lo = (u16*)take((size_t)NH * NH * 2);
  u16* W2aT_hi = (u16*)take((size_t)NH * NH * 2);
  u16* W2aT_lo = (u16*)take((size_t)NH * NH * 2);
  int* deg    = (int*)take((size_t)NN * 4);
  int* cursor = (int*)take((size_t)NN * 4);
  int* rowptr = (int*)take((size_t)(NN + 1) * 4);
  int* csr    = (int*)take((size_t)NE * 4);
  int* bsum   = (int*)take((size_t)NB * 4);
  int* boff   = (int*)take((size_t)NB * 4);
  float* svec = (float*)take((size_t)NH * 4);

  (void)hipMemsetAsync(svec, 0, NH * 4, stream);
  (void)hipMemsetAsync(deg, 0, (size_t)NN * 4, stream);

  // fused prologue: 3x weight hi/lo transpose + x->bf16
  PrepArgs pa;
  pa.W1a = W1a; pa.W1aT_hi = W1aT_hi; pa.W1aT_lo = W1aT_lo;
  pa.W1b = W1b; pa.W1bT_hi = W1bT_hi; pa.W1bT_lo = W1bT_lo;
  pa.W2a = W2a; pa.W2aT_hi = W2aT_hi; pa.W2aT_lo = W2aT_lo;
  pa.x4 = (const float4*)x; pa.xb = (uint64_t*)xb;
  prep_all<<<2304 + (MPAD * 32 + 255) / 256, 256, 0, stream>>>(pa);

  // CSR: deg -> parallel exclusive scan -> rowptr/cursor -> csr
  hist_dst<<<(NE + 255) / 256, 256, 0, stream>>>(ei, deg);
  deg_partial<<<NB, 256, 0, stream>>>(deg, bsum);
  scan_bsum<<<1, 256, 0, stream>>>(bsum, boff, rowptr);
  scan_apply<<<NB, 256, 0, stream>>>(deg, boff, rowptr, cursor);
  fill_csr<<<(NE + 255) / 256, 256, 0, stream>>>(ei, cursor, csr);

  // conv1: gather (bf16) + MLP; h1 stored fp8
  gather_x<<<(MPAD + 3) / 4, 256, 0, stream>>>(xb, rowptr, csr, hb1);
  gemm_bt<ND, 0><<<(MPAD / 128) * 4, 256, 0, stream>>>(hb1, W1aT_hi, W1aT_lo, b1a, R, nullptr, nullptr);
  gemm_bt<NH, 1><<<(MPAD / 128) * 4, 256, 0, stream>>>(R, W1bT_hi, W1bT_lo, b1b, nullptr, H8, nullptr);

  // conv2: gather fp8 (r2 overwrites R) + first layer fused with relu+mean-pool
  gather_h<<<(MPAD + 3) / 4, 256, 0, stream>>>(H8, rowptr, csr, R);
  gemm_bt<NH, 2><<<(MPAD / 128) * 4, 256, 0, stream>>>(R, W2aT_hi, W2aT_lo, b2a, nullptr, nullptr, svec);

  // pooled @ W2b + b2b then @ Wf + bf
  final_fuse<<<1, NH, 0, stream>>>(svec, W2b, b2b, Wf, bfv, out);
}

// Round 10
// 328.515 us; speedup vs baseline: 1.4943x; 1.0835x over previous
//
#include <hip/hip_runtime.h>
#include <stdint.h>

#define NN 50000
#define NE 600000
#define ND 128
#define NH 512
#define NO 128
#define MPAD 50048  // 391 * 128
#define NB 196      // ceil(NN/256) scan blocks

typedef unsigned short u16;
typedef uint8_t u8;
typedef __attribute__((ext_vector_type(8))) short bf16x8;
typedef __attribute__((ext_vector_type(4))) float f32x4;
typedef __attribute__((ext_vector_type(2))) float f32x2;

__device__ __forceinline__ u16 f2bf(float f) {
  union { float f; uint32_t u; } v; v.f = f;
  uint32_t u = v.u;
  uint32_t r = (u + 0x7fffu + ((u >> 16) & 1u)) >> 16;
  return (u16)r;
}
__device__ __forceinline__ float bf2f(u16 h) {
  union { uint32_t u; float f; } v; v.u = ((uint32_t)h) << 16; return v.f;
}
__device__ __forceinline__ uint64_t f42bfq(float4 v) {
  union { u16 u[4]; uint64_t q; } o;
  o.u[0] = f2bf(v.x); o.u[1] = f2bf(v.y); o.u[2] = f2bf(v.z); o.u[3] = f2bf(v.w);
  return o.q;
}

// ---- fp8 e4m3 (OCP) encode/decode: HW cvt on gfx950, SW fallback ----
#if defined(__has_builtin)
#if __has_builtin(__builtin_amdgcn_cvt_pk_f32_fp8) && __has_builtin(__builtin_amdgcn_cvt_pk_fp8_f32)
#define HW_FP8 1
#endif
#endif
#ifndef HW_FP8
#define HW_FP8 0
#endif

__device__ __forceinline__ u8 f2fp8(float f) {
#if HW_FP8
  return (u8)(__builtin_amdgcn_cvt_pk_fp8_f32(f, f, 0, false) & 0xff);
#else
  union { float f; uint32_t u; } v; v.f = f;
  uint32_t s = v.u >> 31;
  float a = fabsf(f);
  if (a >= 448.f) return (u8)((s << 7) | 0x7e);
  if (a < 0.015625f) {
    uint32_t m = (uint32_t)(a * 512.0f + 0.5f);
    if (m > 7) return (u8)((s << 7) | 8);
    return (u8)((s << 7) | m);
  }
  uint32_t u = v.u & 0x7fffffff;
  uint32_t r = u + 0x7FFFF + ((u >> 20) & 1);
  int e8 = (int)(r >> 23) - 120;
  if (e8 >= 16) return (u8)((s << 7) | 0x7e);
  return (u8)((s << 7) | ((uint32_t)e8 << 3) | ((r >> 20) & 7));
#endif
}

template<bool HI>
__device__ __forceinline__ f32x2 fp8x2_f32(uint32_t w) {
#if HW_FP8
  return __builtin_amdgcn_cvt_pk_f32_fp8((int)w, HI);
#else
  uint32_t h = HI ? (w >> 16) : w;
  f32x2 r;
  for (int i = 0; i < 2; ++i) {
    uint32_t b = (h >> (i * 8)) & 0xff;
    uint32_t s = (b >> 7) & 1, e = (b >> 3) & 15, m = b & 7;
    float t;
    if (e == 0) t = (float)m * 0.001953125f;
    else { union { uint32_t u; float f; } v; v.u = ((e + 120) << 23) | (m << 20); t = v.f; }
    r[i] = s ? -t : t;
  }
  return r;
#endif
}

__device__ __forceinline__ void gld16(const u16* g, u16* l) {
  __builtin_amdgcn_global_load_lds(
      (const __attribute__((address_space(1))) void*)g,
      (__attribute__((address_space(3))) void*)l, 16, 0, 0);
}

// ---------------------------------------------------------------------------
// GEMM: C[M,512] = A[M,K](bf16) @ B^T   B stored transposed [512,K] bf16
// (round-7 structure minus the lo-weight path: A,B staged via
//  global_load_lds, XOR-swizzled both-sides, 2 barriers/K-step; 1-D grid +
//  bijective XCD remap, m=wgid>>2 n=wgid&3 for A-tile L2 reuse.)
// EPI 0: relu -> bf16 store ; EPI 1: plain -> fp8 store (H) ;
// EPI 2: relu -> guarded column-sum atomicAdd into sumOut[512]
// ---------------------------------------------------------------------------
template<int K, int EPI>
__global__ __launch_bounds__(256) void gemm_bt(
    const u16* __restrict__ A, const u16* __restrict__ B,
    const float* __restrict__ bias,
    u16* __restrict__ outB, u8* __restrict__ outF8,
    float* __restrict__ sumOut)
{
  __shared__ u16 As[128 * 64];
  __shared__ u16 Bs[128 * 64];
  const int nwg  = gridDim.x;
  const int q    = nwg >> 3, r = nwg & 7;
  const int xcd  = blockIdx.x & 7, loc = blockIdx.x >> 3;
  const int wgid = (xcd < r ? xcd * (q + 1) : r * (q + 1) + (xcd - r) * q) + loc;
  const int m0   = (wgid >> 2) * 128;
  const int n0   = (wgid & 3) * 128;

  const int tid  = threadIdx.x;
  const int w    = tid >> 6;
  const int lane = tid & 63;
  const int wm   = (w >> 1) * 64;
  const int wn   = (w & 1) * 64;
  const int l15  = lane & 15;
  const int lh   = lane >> 4;

  const f32x4 z4 = {0.f, 0.f, 0.f, 0.f};
  f32x4 acc[4][4];
#pragma unroll
  for (int m = 0; m < 4; ++m)
#pragma unroll
    for (int n = 0; n < 4; ++n) acc[m][n] = z4;

  for (int k0 = 0; k0 < K; k0 += 64) {
#pragma unroll
    for (int i = 0; i < 4; ++i) {
      const int cc  = i * 256 + w * 64 + lane;     // 16B chunk id, lane-contig
      const int row = cc >> 3;
      const int csw = (cc ^ row) & 7;              // swizzled source chunk
      const int ldsbase = (i * 256 + w * 64) * 8;  // u16 units, wave-uniform (linear)
      gld16(A + (size_t)(m0 + row) * K + k0 + csw * 8, As + ldsbase);
      gld16(B + (size_t)(n0 + row) * K + k0 + csw * 8, Bs + ldsbase);
    }
    __syncthreads();
#pragma unroll
    for (int ks = 0; ks < 2; ++ks) {
      bf16x8 a[4], b[4];
#pragma unroll
      for (int m = 0; m < 4; ++m) {
        const int row = wm + m * 16 + l15;
        const int ch  = (ks * 4 + lh) ^ (row & 7);
        a[m] = *(const bf16x8*)&As[row * 64 + ch * 8];
      }
#pragma unroll
      for (int n = 0; n < 4; ++n) {
        const int row = wn + n * 16 + l15;
        const int ch  = (ks * 4 + lh) ^ (row & 7);
        b[n] = *(const bf16x8*)&Bs[row * 64 + ch * 8];
      }
#pragma unroll
      for (int m = 0; m < 4; ++m)
#pragma unroll
        for (int n = 0; n < 4; ++n)
          acc[m][n] = __builtin_amdgcn_mfma_f32_16x16x32_bf16(a[m], b[n], acc[m][n], 0, 0, 0);
    }
    __syncthreads();
  }

  if (EPI == 2) {
#pragma unroll
    for (int n = 0; n < 4; ++n) {
      const int gc = n0 + wn + n * 16 + l15;
      const float bv = bias[gc];
      float p = 0.f;
#pragma unroll
      for (int m = 0; m < 4; ++m) {
        const int rbase = m0 + wm + m * 16 + lh * 4;
#pragma unroll
        for (int j = 0; j < 4; ++j) {
          if (rbase + j < NN) p += fmaxf(acc[m][n][j] + bv, 0.f);
        }
      }
      p += __shfl_xor(p, 16);
      p += __shfl_xor(p, 32);
      if (lane < 16) atomicAdd(&sumOut[gc], p);
    }
  } else {
#pragma unroll
    for (int m = 0; m < 4; ++m) {
#pragma unroll
      for (int j = 0; j < 4; ++j) {
        const int gr = m0 + wm + m * 16 + lh * 4 + j;
#pragma unroll
        for (int n = 0; n < 4; ++n) {
          const int gc = n0 + wn + n * 16 + l15;
          const float v = acc[m][n][j] + bias[gc];
          if (EPI == 0) outB[(size_t)gr * NH + gc] = f2bf(fmaxf(v, 0.f));
          else          outF8[(size_t)gr * NH + gc] = f2fp8(v);
        }
      }
    }
  }
}

// ---------------------------------------------------------------------------
// Fused prologue prep: one launch does
//  region 0: W1a [128x512]  -> W1aT bf16    (256 blocks)
//  region 1: W1b [512x512]  -> W1bT bf16    (1024 blocks)
//  region 2: W2a [512x512]  -> W2aT bf16    (1024 blocks)
//  region 3: x f32 -> bf16 padded           (6256 blocks, 4 cols/thread)
// ---------------------------------------------------------------------------
struct PrepArgs {
  const float* W1a; u16* W1aT;
  const float* W1b; u16* W1bT;
  const float* W2a; u16* W2aT;
  const float4* x4; uint64_t* xb;
};

__device__ __forceinline__ void cvtWT_one(const float* W, u16* T,
                                          int Kd, int Nd, int t) {
  if (t >= Kd * Nd) return;
  int k = t / Nd, n = t - k * Nd;
  T[n * Kd + k] = f2bf(W[t]);
}

__global__ __launch_bounds__(256) void prep_all(PrepArgs p) {
  const int bid = blockIdx.x;
  if (bid < 256) {
    cvtWT_one(p.W1a, p.W1aT, ND, NH, bid * 256 + threadIdx.x);
  } else if (bid < 1280) {
    cvtWT_one(p.W1b, p.W1bT, NH, NH, (bid - 256) * 256 + threadIdx.x);
  } else if (bid < 2304) {
    cvtWT_one(p.W2a, p.W2aT, NH, NH, (bid - 1280) * 256 + threadIdx.x);
  } else {
    int t = (bid - 2304) * 256 + threadIdx.x;
    if (t >= MPAD * 32) return;
    int row = t >> 5;
    uint64_t qv = 0;
    if (row < NN) qv = f42bfq(p.x4[t]);
    p.xb[t] = qv;
  }
}

// ---------------- CSR construction ----------------
__global__ void hist_dst(const int* __restrict__ ei, int* __restrict__ deg) {
  int e = blockIdx.x * 256 + threadIdx.x;
  if (e < NE) atomicAdd(&deg[ei[NE + e]], 1);
}

__global__ void deg_partial(const int* __restrict__ deg, int* __restrict__ bsum) {
  const int i = blockIdx.x * 256 + threadIdx.x;
  int v = (i < NN) ? deg[i] : 0;
#pragma unroll
  for (int o = 1; o < 64; o <<= 1) v += __shfl_xor(v, o);
  __shared__ int ws[4];
  if ((threadIdx.x & 63) == 0) ws[threadIdx.x >> 6] = v;
  __syncthreads();
  if (threadIdx.x == 0) bsum[blockIdx.x] = ws[0] + ws[1] + ws[2] + ws[3];
}

__global__ void scan_bsum(const int* __restrict__ bsum, int* __restrict__ boff,
                          int* __restrict__ rowptr) {
  __shared__ int s[256];
  const int t = threadIdx.x;
  int v = (t < NB) ? bsum[t] : 0;
  s[t] = v;
  __syncthreads();
  for (int o = 1; o < 256; o <<= 1) {
    int u = (t >= o) ? s[t - o] : 0;
    __syncthreads();
    s[t] += u;
    __syncthreads();
  }
  if (t < NB) boff[t] = s[t] - v;
  if (t == 0) rowptr[NN] = NE;
}

__global__ void scan_apply(const int* __restrict__ deg, const int* __restrict__ boff,
                           int* __restrict__ rowptr, int* __restrict__ cursor) {
  __shared__ int s[256];
  const int t = threadIdx.x;
  const int i = blockIdx.x * 256 + t;
  int v = (i < NN) ? deg[i] : 0;
  s[t] = v;
  __syncthreads();
  for (int o = 1; o < 256; o <<= 1) {
    int u = (t >= o) ? s[t - o] : 0;
    __syncthreads();
    s[t] += u;
    __syncthreads();
  }
  if (i < NN) {
    int ex = boff[blockIdx.x] + s[t] - v;
    rowptr[i] = ex;
    cursor[i] = ex;
  }
}

__global__ void fill_csr(const int* __restrict__ ei, int* __restrict__ cursor,
                         int* __restrict__ csr) {
  int e = blockIdx.x * 256 + threadIdx.x;
  if (e >= NE) return;
  int d = ei[NE + e];
  int p = atomicAdd(&cursor[d], 1);
  csr[p] = ei[e];
}

// ---------------- gather-reduce aggregations ----------------
// conv1: hb1[i][:] = bf16( xb[i][:] + sum_{e} xb[csr[e]][:] )  (xb bf16, dim 128)
__global__ __launch_bounds__(256) void gather_x(
    const u16* __restrict__ xb, const int* __restrict__ rowptr,
    const int* __restrict__ csr, u16* __restrict__ hb1) {
  const int wid  = blockIdx.x * 4 + (threadIdx.x >> 6);
  const int lane = threadIdx.x & 63;
  if (wid >= MPAD) return;
  float a0 = 0.f, a1 = 0.f;
  if (wid < NN) {
    uint32_t v = *(const uint32_t*)(xb + (size_t)wid * ND + lane * 2);
    a0 = bf2f((u16)v); a1 = bf2f((u16)(v >> 16));
    const int beg = rowptr[wid], end = rowptr[wid + 1];
    int e = beg;
    for (; e + 1 < end; e += 2) {
      int s0 = csr[e], s1 = csr[e + 1];
      uint32_t v0 = *(const uint32_t*)(xb + (size_t)s0 * ND + lane * 2);
      uint32_t v1 = *(const uint32_t*)(xb + (size_t)s1 * ND + lane * 2);
      a0 += bf2f((u16)v0) + bf2f((u16)v1);
      a1 += bf2f((u16)(v0 >> 16)) + bf2f((u16)(v1 >> 16));
    }
    if (e < end) {
      int s0 = csr[e];
      uint32_t v0 = *(const uint32_t*)(xb + (size_t)s0 * ND + lane * 2);
      a0 += bf2f((u16)v0);
      a1 += bf2f((u16)(v0 >> 16));
    }
  }
  uint32_t o = (uint32_t)f2bf(a0) | ((uint32_t)f2bf(a1) << 16);
  *(uint32_t*)(hb1 + (size_t)wid * ND + lane * 2) = o;
}

// fp8 x8 decode -> packed f32x2 accumulate (v_pk_add_f32)
__device__ __forceinline__ void acc_fp8x8(f32x2* acc, uint2 v) {
  acc[0] += fp8x2_f32<false>(v.x);
  acc[1] += fp8x2_f32<true >(v.x);
  acc[2] += fp8x2_f32<false>(v.y);
  acc[3] += fp8x2_f32<true >(v.y);
}

// conv2: r2[i][:] = bf16( H8[i][:] + sum_{e} H8[csr[e]][:] )  (H8 fp8, dim 512)
__global__ __launch_bounds__(256) void gather_h(
    const u8* __restrict__ H8, const int* __restrict__ rowptr,
    const int* __restrict__ csr, u16* __restrict__ r2) {
  const int wid  = blockIdx.x * 4 + (threadIdx.x >> 6);
  const int lane = threadIdx.x & 63;
  if (wid >= MPAD) return;
  f32x2 acc[4];
#pragma unroll
  for (int j = 0; j < 4; ++j) acc[j] = (f32x2){0.f, 0.f};
  if (wid < NN) {
    acc_fp8x8(acc, *(const uint2*)(H8 + (size_t)wid * NH + lane * 8));
    const int beg = rowptr[wid], end = rowptr[wid + 1];
    int e = beg;
    for (; e + 1 < end; e += 2) {
      int s0 = csr[e], s1 = csr[e + 1];
      uint2 v0 = *(const uint2*)(H8 + (size_t)s0 * NH + lane * 8);
      uint2 v1 = *(const uint2*)(H8 + (size_t)s1 * NH + lane * 8);
      acc_fp8x8(acc, v0);
      acc_fp8x8(acc, v1);
    }
    if (e < end) {
      int s0 = csr[e];
      acc_fp8x8(acc, *(const uint2*)(H8 + (size_t)s0 * NH + lane * 8));
    }
  }
  union { u16 u[8]; uint4 q; } o;
#pragma unroll
  for (int j = 0; j < 4; ++j) {
    o.u[j * 2]     = f2bf(acc[j].x);
    o.u[j * 2 + 1] = f2bf(acc[j].y);
  }
  *(uint4*)(r2 + (size_t)wid * NH + lane * 8) = o.q;
}

// out[128] = ((s/NN) @ W2b + b2b) @ Wf + bf   (all f32)
__global__ void final_fuse(const float* __restrict__ s, const float* __restrict__ W2b,
                           const float* __restrict__ b2b, const float* __restrict__ Wf,
                           const float* __restrict__ bfv, float* __restrict__ out) {
  __shared__ float pooled[NH];
  const int j = threadIdx.x;
  const float invN = 1.0f / (float)NN;
  float acc = b2b[j];
  for (int k = 0; k < NH; ++k) acc += s[k] * invN * W2b[k * NH + j];
  pooled[j] = acc;
  __syncthreads();
  if (j < NO) {
    float o = bfv[j];
    for (int k = 0; k < NH; ++k) o += pooled[k] * Wf[k * NO + j];
    out[j] = o;
  }
}

__global__ void ws_sentinel(float* out) {
  if (threadIdx.x < NO) out[threadIdx.x] = -12345.0f;
}

extern "C" void kernel_launch(void* const* d_in, const int* in_sizes, int n_in,
                              void* d_out, int out_size, void* d_ws, size_t ws_size,
                              hipStream_t stream) {
  const float* x   = (const float*)d_in[0];
  const int*   ei  = (const int*)d_in[1];
  const float* W1a = (const float*)d_in[2];
  const float* b1a = (const float*)d_in[3];
  const float* W1b = (const float*)d_in[4];
  const float* b1b = (const float*)d_in[5];
  const float* W2a = (const float*)d_in[6];
  const float* b2a = (const float*)d_in[7];
  const float* W2b = (const float*)d_in[8];
  const float* b2b = (const float*)d_in[9];
  const float* Wf  = (const float*)d_in[10];
  const float* bfv = (const float*)d_in[11];
  float* out = (float*)d_out;

  const size_t XB  = (size_t)MPAD * ND * 2;  // 12.8 MB bf16 x
  const size_t HB1 = (size_t)MPAD * ND * 2;  // 12.8 MB bf16 agg1
  const size_t RB  = (size_t)MPAD * NH * 2;  // 51.25 MB bf16 (r1, then r2)
  const size_t H8B = (size_t)MPAD * NH;      // 25.6 MB fp8 (h1)
  const size_t WB  = (size_t)NH * ND * 2 + 2 * (size_t)NH * NH * 2;
  const size_t CSRB = (size_t)(NN + 1) * 4 + 2 * (size_t)NN * 4 + (size_t)NE * 4
                      + 2 * (size_t)NB * 4;
  const size_t NEED = XB + HB1 + RB + H8B + WB + CSRB + NH * 4 + 32 * 256;
  if (ws_size < NEED) {
    ws_sentinel<<<1, 128, 0, stream>>>(out);
    return;
  }

  char* ws = (char*)d_ws;
  size_t off = 0;
  auto take = [&](size_t bytes) {
    char* p = ws + off;
    off = (off + bytes + 255) & ~(size_t)255;
    return p;
  };
  u16* xb  = (u16*)take(XB);
  u16* hb1 = (u16*)take(HB1);
  u16* R   = (u16*)take(RB);
  u8*  H8  = (u8*)take(H8B);
  u16* W1aT = (u16*)take((size_t)NH * ND * 2);
  u16* W1bT = (u16*)take((size_t)NH * NH * 2);
  u16* W2aT = (u16*)take((size_t)NH * NH * 2);
  int* deg    = (int*)take((size_t)NN * 4);
  int* cursor = (int*)take((size_t)NN * 4);
  int* rowptr = (int*)take((size_t)(NN + 1) * 4);
  int* csr    = (int*)take((size_t)NE * 4);
  int* bsum   = (int*)take((size_t)NB * 4);
  int* boff   = (int*)take((size_t)NB * 4);
  float* svec = (float*)take((size_t)NH * 4);

  (void)hipMemsetAsync(svec, 0, NH * 4, stream);
  (void)hipMemsetAsync(deg, 0, (size_t)NN * 4, stream);

  // fused prologue: 3x weight transpose (bf16) + x->bf16
  PrepArgs pa;
  pa.W1a = W1a; pa.W1aT = W1aT;
  pa.W1b = W1b; pa.W1bT = W1bT;
  pa.W2a = W2a; pa.W2aT = W2aT;
  pa.x4 = (const float4*)x; pa.xb = (uint64_t*)xb;
  prep_all<<<2304 + (MPAD * 32 + 255) / 256, 256, 0, stream>>>(pa);

  // CSR: deg -> parallel exclusive scan -> rowptr/cursor -> csr
  hist_dst<<<(NE + 255) / 256, 256, 0, stream>>>(ei, deg);
  deg_partial<<<NB, 256, 0, stream>>>(deg, bsum);
  scan_bsum<<<1, 256, 0, stream>>>(bsum, boff, rowptr);
  scan_apply<<<NB, 256, 0, stream>>>(deg, boff, rowptr, cursor);
  fill_csr<<<(NE + 255) / 256, 256, 0, stream>>>(ei, cursor, csr);

  // conv1: gather (bf16) + MLP; h1 stored fp8
  gather_x<<<(MPAD + 3) / 4, 256, 0, stream>>>(xb, rowptr, csr, hb1);
  gemm_bt<ND, 0><<<(MPAD / 128) * 4, 256, 0, stream>>>(hb1, W1aT, b1a, R, nullptr, nullptr);
  gemm_bt<NH, 1><<<(MPAD / 128) * 4, 256, 0, stream>>>(R, W1bT, b1b, nullptr, H8, nullptr);

  // conv2: gather fp8 (r2 overwrites R) + first layer fused with relu+mean-pool
  gather_h<<<(MPAD + 3) / 4, 256, 0, stream>>>(H8, rowptr, csr, R);
  gemm_bt<NH, 2><<<(MPAD / 128) * 4, 256, 0, stream>>>(R, W2aT, b2a, nullptr, nullptr, svec);

  // pooled @ W2b + b2b then @ Wf + bf
  final_fuse<<<1, NH, 0, stream>>>(svec, W2b, b2b, Wf, bfv, out);
}